// Round 3
// baseline (1027.475 us; speedup 1.0000x reference)
//
#include <hip/hip_runtime.h>
#include <hip/hip_bf16.h>

#define SEQ      1024
#define BATCH    4
#define NHEADS   16
#define HDIM     64
#define DMODEL   1024
#define DGRAPH   8
#define QK_SCALE 0.125f
#define NEG_INF  (-1.0e9f)

// ---------------------------------------------------------------------------
// Projection GEMM: C[4096][1024] = X[4096][1024] * W[1024][1024]^T + bias
// W is row-major [out_col][k] (a 1024-row slice of the fused weight).
// Tile: BM=128 x BN=64, BK=16, 256 threads, 8x4 micro-tile.
// HEADSPLIT=1 scatters output to [B][H][N][HDIM] layout.
// ---------------------------------------------------------------------------
template<int HEADSPLIT>
__global__ __launch_bounds__(256) void proj_gemm(
    const float* __restrict__ X,
    const float* __restrict__ W,
    const float* __restrict__ bias,
    float* __restrict__ Y)
{
    __shared__ float At[16][132];  // [k][row], pad->2-way-free transpose writes
    __shared__ float Bt[16][68];   // [k][col]

    const int t  = threadIdx.x;
    const int tx = t & 15;         // 16 col groups * 4 = 64 cols
    const int ty = t >> 4;         // 16 row groups * (4+4) = 128 rows
    const int m0 = blockIdx.y * 128;
    const int c0 = blockIdx.x * 64;

    float acc[8][4];
#pragma unroll
    for (int i = 0; i < 8; ++i)
#pragma unroll
        for (int j = 0; j < 4; ++j) acc[i][j] = 0.f;

    for (int kt = 0; kt < 64; ++kt) {
        // stage A (128x16), transposed: 2 float4 per thread
#pragma unroll
        for (int i = 0; i < 2; ++i) {
            int f4 = t + i * 256;
            int row = f4 >> 2;
            int kq  = f4 & 3;
            float4 v = *reinterpret_cast<const float4*>(
                X + (size_t)(m0 + row) * DMODEL + kt * 16 + kq * 4);
            At[kq * 4 + 0][row] = v.x; At[kq * 4 + 1][row] = v.y;
            At[kq * 4 + 2][row] = v.z; At[kq * 4 + 3][row] = v.w;
        }
        // stage B (64x16), transposed: 1 float4 per thread
        {
            int col = t >> 2;
            int kq  = t & 3;
            float4 v = *reinterpret_cast<const float4*>(
                W + (size_t)(c0 + col) * DMODEL + kt * 16 + kq * 4);
            Bt[kq * 4 + 0][col] = v.x; Bt[kq * 4 + 1][col] = v.y;
            Bt[kq * 4 + 2][col] = v.z; Bt[kq * 4 + 3][col] = v.w;
        }
        __syncthreads();
#pragma unroll
        for (int k = 0; k < 16; ++k) {
            float4 a0 = *reinterpret_cast<const float4*>(&At[k][ty * 4]);
            float4 a1 = *reinterpret_cast<const float4*>(&At[k][64 + ty * 4]);
            float4 b0 = *reinterpret_cast<const float4*>(&Bt[k][tx * 4]);
            float av[8] = {a0.x, a0.y, a0.z, a0.w, a1.x, a1.y, a1.z, a1.w};
            float bv[4] = {b0.x, b0.y, b0.z, b0.w};
#pragma unroll
            for (int i = 0; i < 8; ++i)
#pragma unroll
                for (int j = 0; j < 4; ++j)
                    acc[i][j] = fmaf(av[i], bv[j], acc[i][j]);
        }
        __syncthreads();
    }

    float4 bv4 = *reinterpret_cast<const float4*>(bias + c0 + tx * 4);
    float bb[4] = {bv4.x, bv4.y, bv4.z, bv4.w};
    const int c = c0 + tx * 4;
#pragma unroll
    for (int i = 0; i < 8; ++i) {
        int r = m0 + ((i < 4) ? (ty * 4 + i) : (64 + ty * 4 + (i - 4)));
        float4 o;
        o.x = acc[i][0] + bb[0]; o.y = acc[i][1] + bb[1];
        o.z = acc[i][2] + bb[2]; o.w = acc[i][3] + bb[3];
        if (HEADSPLIT) {
            int b_ = r >> 10, n = r & 1023;
            int h = c >> 6, d = c & 63;
            *reinterpret_cast<float4*>(
                Y + ((size_t)((b_ * NHEADS + h) * SEQ + n)) * HDIM + d) = o;
        } else {
            *reinterpret_cast<float4*>(Y + (size_t)r * DMODEL + c) = o;
        }
    }
}

// ---------------------------------------------------------------------------
// Graph bias: attL[b][h][n][m] = sum_p dists[b][n][m][p] * wg[h][p]
// Each thread: 4 consecutive m, all 16 heads (dists read exactly once).
// ---------------------------------------------------------------------------
__global__ __launch_bounds__(256) void graph_bias_kernel(
    const float* __restrict__ dists,
    const float* __restrict__ wg,
    float* __restrict__ attL)
{
    __shared__ float wgs[NHEADS * DGRAPH];
    const int t = threadIdx.x;
    if (t < NHEADS * DGRAPH) wgs[t] = wg[t];
    __syncthreads();

    size_t idx = (size_t)blockIdx.x * 256 + t;
    int mq = (int)(idx & 255);
    int n  = (int)((idx >> 8) & 1023);
    int b  = (int)(idx >> 18);
    int m  = mq * 4;

    const float* dp = dists + (((size_t)(b * SEQ + n)) * SEQ + m) * DGRAPH;
    float d[4][8];
#pragma unroll
    for (int i = 0; i < 8; ++i) {
        float4 v = *reinterpret_cast<const float4*>(dp + i * 4);
        d[i >> 1][(i & 1) * 4 + 0] = v.x; d[i >> 1][(i & 1) * 4 + 1] = v.y;
        d[i >> 1][(i & 1) * 4 + 2] = v.z; d[i >> 1][(i & 1) * 4 + 3] = v.w;
    }
#pragma unroll
    for (int h = 0; h < NHEADS; ++h) {
        float ov[4];
#pragma unroll
        for (int jm = 0; jm < 4; ++jm) {
            float s = 0.f;
#pragma unroll
            for (int p = 0; p < DGRAPH; ++p)
                s = fmaf(d[jm][p], wgs[h * DGRAPH + p], s);
            ov[jm] = s;
        }
        float4 o; o.x = ov[0]; o.y = ov[1]; o.z = ov[2]; o.w = ov[3];
        *reinterpret_cast<float4*>(
            attL + (((size_t)((b * NHEADS + h) * SEQ + n)) * SEQ + m)) = o;
    }
}

// ---------------------------------------------------------------------------
// QK^T: attL[bh][n][m] = mask[b][n] ? NEG_INF : attL + (Q.K)*SCALE
// Per (b,h): 128x128 tile over n x m, full Dh=64 inner, 8x8 micro.
// ---------------------------------------------------------------------------
__global__ __launch_bounds__(256) void qk_kernel(
    const float* __restrict__ QH,
    const float* __restrict__ KH,
    const int* __restrict__ mask,
    float* __restrict__ attL)
{
    __shared__ float QT[64][132];  // [d][n]
    __shared__ float KT[64][132];  // [d][m]
    __shared__ int maskS[128];

    const int t  = threadIdx.x;
    const int tx = t & 15;
    const int ty = t >> 4;
    const int m0 = blockIdx.x * 128;
    const int n0 = blockIdx.y * 128;
    const int bh = blockIdx.z;
    const int b  = bh >> 4;

    const float* Qbase = QH + ((size_t)bh * SEQ + n0) * HDIM;
    const float* Kbase = KH + ((size_t)bh * SEQ + m0) * HDIM;
    if (t < 128) maskS[t] = mask[b * SEQ + n0 + t];

#pragma unroll
    for (int i = 0; i < 8; ++i) {
        int f4 = t + i * 256;
        int row = f4 >> 4;  // 0..127
        int dq  = f4 & 15;
        float4 q = *reinterpret_cast<const float4*>(Qbase + (size_t)row * HDIM + dq * 4);
        QT[dq * 4 + 0][row] = q.x; QT[dq * 4 + 1][row] = q.y;
        QT[dq * 4 + 2][row] = q.z; QT[dq * 4 + 3][row] = q.w;
        float4 kv = *reinterpret_cast<const float4*>(Kbase + (size_t)row * HDIM + dq * 4);
        KT[dq * 4 + 0][row] = kv.x; KT[dq * 4 + 1][row] = kv.y;
        KT[dq * 4 + 2][row] = kv.z; KT[dq * 4 + 3][row] = kv.w;
    }
    __syncthreads();

    float acc[8][8];
#pragma unroll
    for (int i = 0; i < 8; ++i)
#pragma unroll
        for (int j = 0; j < 8; ++j) acc[i][j] = 0.f;

#pragma unroll 8
    for (int d = 0; d < 64; ++d) {
        float4 a0 = *reinterpret_cast<const float4*>(&QT[d][ty * 4]);
        float4 a1 = *reinterpret_cast<const float4*>(&QT[d][64 + ty * 4]);
        float4 b0 = *reinterpret_cast<const float4*>(&KT[d][tx * 4]);
        float4 b1 = *reinterpret_cast<const float4*>(&KT[d][64 + tx * 4]);
        float av[8] = {a0.x, a0.y, a0.z, a0.w, a1.x, a1.y, a1.z, a1.w};
        float bv[8] = {b0.x, b0.y, b0.z, b0.w, b1.x, b1.y, b1.z, b1.w};
#pragma unroll
        for (int i = 0; i < 8; ++i)
#pragma unroll
            for (int j = 0; j < 8; ++j)
                acc[i][j] = fmaf(av[i], bv[j], acc[i][j]);
    }

#pragma unroll
    for (int i = 0; i < 8; ++i) {
        int ri = (i < 4) ? (ty * 4 + i) : (64 + ty * 4 + (i - 4));
        int n  = n0 + ri;
        int masked = maskS[ri];
        float* rowp = attL + ((size_t)bh * SEQ + n) * SEQ + m0;
#pragma unroll
        for (int jg = 0; jg < 2; ++jg) {
            int coff = jg * 64 + tx * 4;
            float4 old = *reinterpret_cast<const float4*>(rowp + coff);
            float4 o;
            if (masked) {
                o.x = NEG_INF; o.y = NEG_INF; o.z = NEG_INF; o.w = NEG_INF;
            } else {
                o.x = fmaf(acc[i][jg * 4 + 0], QK_SCALE, old.x);
                o.y = fmaf(acc[i][jg * 4 + 1], QK_SCALE, old.y);
                o.z = fmaf(acc[i][jg * 4 + 2], QK_SCALE, old.z);
                o.w = fmaf(acc[i][jg * 4 + 3], QK_SCALE, old.w);
            }
            *reinterpret_cast<float4*>(rowp + coff) = o;
        }
    }
}

// ---------------------------------------------------------------------------
// Softmax (in-place, attL -> probabilities) + PV -> AO[b][n][h*64+d]
// Block: (b, h, 64 query rows). Phase A: per-row max & exp-sum (wave/row,
// values held in registers). Phase B: 8 chunks of 128 m; p written to global
// att AND transposed into LDS; V chunk staged; 4x4 micro PV accumulate.
// ---------------------------------------------------------------------------
__global__ __launch_bounds__(256) void softmax_pv_kernel(
    float* __restrict__ attL,
    const float* __restrict__ VH,
    float* __restrict__ AO)
{
    __shared__ float pT[128][68];   // [m][row]
    __shared__ float Vt[128][68];   // [m][d]
    __shared__ float rowMax[64];
    __shared__ float rowInv[64];

    const int t    = threadIdx.x;
    const int lane = t & 63;
    const int w    = t >> 6;
    const int n0   = blockIdx.x * 64;
    const int h    = blockIdx.y;
    const int b    = blockIdx.z;
    const int bh   = b * NHEADS + h;
    float* Lbase = attL + ((size_t)bh * SEQ + n0) * SEQ;

    // Phase A: row statistics (each wave handles 16 rows)
    for (int rr = 0; rr < 16; ++rr) {
        int r = w * 16 + rr;
        const float* rp = Lbase + (size_t)r * SEQ;
        float rv[16];
#pragma unroll
        for (int i = 0; i < 4; ++i) {
            float4 v = *reinterpret_cast<const float4*>(rp + (size_t)(i * 64 + lane) * 4);
            rv[i * 4 + 0] = v.x; rv[i * 4 + 1] = v.y; rv[i * 4 + 2] = v.z; rv[i * 4 + 3] = v.w;
        }
        float mx = rv[0];
#pragma unroll
        for (int i = 1; i < 16; ++i) mx = fmaxf(mx, rv[i]);
#pragma unroll
        for (int off = 32; off >= 1; off >>= 1) mx = fmaxf(mx, __shfl_xor(mx, off));
        float s = 0.f;
#pragma unroll
        for (int i = 0; i < 16; ++i) s += __expf(rv[i] - mx);
#pragma unroll
        for (int off = 32; off >= 1; off >>= 1) s += __shfl_xor(s, off);
        if (lane == 0) { rowMax[r] = mx; rowInv[r] = 1.0f / s; }
    }
    __syncthreads();

    const int tx = t & 15;   // d cols (16*4=64)
    const int ty = t >> 4;   // rows   (16*4=64)
    float acc[4][4];
#pragma unroll
    for (int i = 0; i < 4; ++i)
#pragma unroll
        for (int j = 0; j < 4; ++j) acc[i][j] = 0.f;

    for (int mc = 0; mc < 8; ++mc) {
        // stage p: compute, write att to global, transpose into LDS
#pragma unroll
        for (int i = 0; i < 8; ++i) {
            int f4 = t + i * 256;
            int row = f4 >> 5;   // 0..63
            int mq  = f4 & 31;   // 0..31
            float* ap = Lbase + (size_t)row * SEQ + mc * 128 + mq * 4;
            float4 l4 = *reinterpret_cast<const float4*>(ap);
            float mxv = rowMax[row], iv = rowInv[row];
            float4 p4;
            p4.x = __expf(l4.x - mxv) * iv;
            p4.y = __expf(l4.y - mxv) * iv;
            p4.z = __expf(l4.z - mxv) * iv;
            p4.w = __expf(l4.w - mxv) * iv;
            *reinterpret_cast<float4*>(ap) = p4;
            pT[mq * 4 + 0][row] = p4.x; pT[mq * 4 + 1][row] = p4.y;
            pT[mq * 4 + 2][row] = p4.z; pT[mq * 4 + 3][row] = p4.w;
        }
        // stage V chunk [128][64]
#pragma unroll
        for (int i = 0; i < 8; ++i) {
            int f4 = t + i * 256;
            int m  = f4 >> 4;    // 0..127
            int dq = f4 & 15;
            float4 vv = *reinterpret_cast<const float4*>(
                VH + ((size_t)bh * SEQ + mc * 128 + m) * HDIM + dq * 4);
            *reinterpret_cast<float4*>(&Vt[m][dq * 4]) = vv;
        }
        __syncthreads();
#pragma unroll 8
        for (int m = 0; m < 128; ++m) {
            float4 a  = *reinterpret_cast<const float4*>(&pT[m][ty * 4]);
            float4 b4 = *reinterpret_cast<const float4*>(&Vt[m][tx * 4]);
            float av[4] = {a.x, a.y, a.z, a.w};
            float bv[4] = {b4.x, b4.y, b4.z, b4.w};
#pragma unroll
            for (int i = 0; i < 4; ++i)
#pragma unroll
                for (int j = 0; j < 4; ++j)
                    acc[i][j] = fmaf(av[i], bv[j], acc[i][j]);
        }
        __syncthreads();
    }

#pragma unroll
    for (int i = 0; i < 4; ++i) {
        int n = n0 + ty * 4 + i;
        float4 o; o.x = acc[i][0]; o.y = acc[i][1]; o.z = acc[i][2]; o.w = acc[i][3];
        *reinterpret_cast<float4*>(
            AO + ((size_t)(b * SEQ + n)) * DMODEL + h * HDIM + tx * 4) = o;
    }
}

// ---------------------------------------------------------------------------
extern "C" void kernel_launch(void* const* d_in, const int* in_sizes, int n_in,
                              void* d_out, int out_size, void* d_ws, size_t ws_size,
                              hipStream_t stream) {
    const float* q       = (const float*)d_in[0];
    const float* k       = (const float*)d_in[1];
    const float* v       = (const float*)d_in[2];
    const int*   mask    = (const int*)d_in[3];
    const float* dists   = (const float*)d_in[4];
    const float* weights = (const float*)d_in[5];
    const float* biases  = (const float*)d_in[6];
    const float* wg      = (const float*)d_in[7];

    float* out  = (float*)d_out;
    float* attL = out + (size_t)BATCH * SEQ * DMODEL;          // att region of d_out

    float* ws = (float*)d_ws;
    const size_t HSZ = (size_t)BATCH * NHEADS * SEQ * HDIM;    // 4M floats
    float* QH = ws;
    float* KH = ws + HSZ;
    float* VH = ws + 2 * HSZ;
    float* AO = ws;   // aliases QH: QH is dead after qk_kernel (stream-ordered)

    dim3 gProj(DMODEL / 64, (BATCH * SEQ) / 128);              // (16, 32)
    proj_gemm<1><<<gProj, 256, 0, stream>>>(q, weights,                     biases,            QH);
    proj_gemm<1><<<gProj, 256, 0, stream>>>(k, weights + 1 * DMODEL * DMODEL, biases + DMODEL,   KH);
    proj_gemm<1><<<gProj, 256, 0, stream>>>(v, weights + 2 * (size_t)DMODEL * DMODEL, biases + 2 * DMODEL, VH);

    graph_bias_kernel<<<(BATCH * SEQ * (SEQ / 4)) / 256, 256, 0, stream>>>(dists, wg, attL);

    dim3 gQK(SEQ / 128, SEQ / 128, BATCH * NHEADS);            // (8, 8, 64)
    qk_kernel<<<gQK, 256, 0, stream>>>(QH, KH, mask, attL);

    dim3 gPV(SEQ / 64, NHEADS, BATCH);                         // (16, 16, 4)
    softmax_pv_kernel<<<gPV, 256, 0, stream>>>(attL, VH, AO);

    proj_gemm<0><<<gProj, 256, 0, stream>>>(AO, weights + 3 * (size_t)DMODEL * DMODEL,
                                            biases + 3 * DMODEL, out);
}